// Round 8
// baseline (345.328 us; speedup 1.0000x reference)
//
#include <hip/hip_runtime.h>

// LNKillingRelu: out = where(kf<=0, x, x + kf*d)
//   d[b,g,k,n]  = sum_f W[g,f] x[b,f,k,n]          (bf16 MFMA GEMM, K=512)
//   kf[b,g,n]   = sum_{k,l} x[b,g,k,n] G[k,l] d[b,g,l,n]   (fp32, G = sl3 Killing)
// x: [8,512,8,2048] f32, W: [512,512] f32, out same shape as x.
//
// R8 = R7 (LDS-free fragment-direct GEMM) with the coverage bug fixed:
// gt now 0..3, g0 = gt*128, grid 4096 — every block covers exactly its 128
// g-rows, all 512 rows written once. R7 covered only half the rows (gt in
// {0,1} with g0 = gt*256). No other changes, clean read of the no-barrier
// hypothesis: fragments loaded straight from prepacked global tiles
// (16B/lane contiguous), sharing via L1 (4 waves, same 8KB B tile) and L2
// (4 gt-blocks back-to-back on one XCD share each 128KB xp tile; W resident).

typedef short bf16x8 __attribute__((ext_vector_type(8)));
typedef float f32x4 __attribute__((ext_vector_type(4)));

__device__ __forceinline__ unsigned short f2bf(float f) {
  unsigned int u = __float_as_uint(f);
  u += 0x7fffu + ((u >> 16) & 1u);   // round-to-nearest-even
  return (unsigned short)(u >> 16);
}

// ---------------- prepass: pack x -> bf16 tiles ----------------
// chunk cid = (((b*128+nt)*16+kt)*4+kg)*128 + c ; element = cid*8 + j
//   where c = k*16+nn, f = kt*32+kg*8+j. Per (b,nt,kt): one 8KB frag-ready tile.
__global__ __launch_bounds__(256) void prepack_x(const float* __restrict__ x,
                                                 short* __restrict__ xp) {
  const int cid = blockIdx.x * 256 + threadIdx.x;    // 8,388,608 chunks
  const int c = cid & 127;
  int t = cid >> 7;
  const int kg = t & 3;  t >>= 2;
  const int kt = t & 15; t >>= 4;
  const int nt = t & 127; t >>= 7;
  const int b = t;
  const int f0 = kt * 32 + kg * 8;
  const float* src = x + ((size_t)(b * 512 + f0) * 8 + (c >> 4)) * 2048
                       + nt * 16 + (c & 15);
  bf16x8 v;
#pragma unroll
  for (int j = 0; j < 8; ++j) v[j] = (short)f2bf(src[(size_t)j * 16384]);
  *(bf16x8*)&xp[(size_t)cid * 8] = v;
}

// ---------------- prepass: pack W -> bf16 tiles ----------------
// chunk cid = ((gq*16+kt)*4+kg)*128 + m ; element = cid*8 + j ; f = kt*32+kg*8+j
// gq = 128-row group of W (0..3), m = row within group.
__global__ __launch_bounds__(256) void prepack_w(const float* __restrict__ W,
                                                 short* __restrict__ wp) {
  const int cid = blockIdx.x * 256 + threadIdx.x;    // 32768 chunks
  const int m = cid & 127;
  int t = cid >> 7;
  const int kg = t & 3;  t >>= 2;
  const int kt = t & 15; t >>= 4;
  const int gq = t;
  const float* src = W + (size_t)(gq * 128 + m) * 512 + kt * 32 + kg * 8;
  bf16x8 v;
#pragma unroll
  for (int j = 0; j < 8; ++j) v[j] = (short)f2bf(src[j]);
  *(bf16x8*)&wp[(size_t)cid * 8] = v;
}

// ---------------- main fused GEMM + Killing epilogue (LDS-free) ----------------
__global__ __launch_bounds__(256, 3) void lnkill_gemm_nolds(
    const short* __restrict__ xp, const short* __restrict__ wp,
    const float* __restrict__ x, float* __restrict__ out) {
  const int tid   = threadIdx.x;
  const int lane  = tid & 63;
  const int w     = tid >> 6;       // wave 0..3; wave owns 32 g-rows
  const int klane = lane >> 4;      // k-group (kg) 0..3
  const int li    = lane & 15;

  // XCD-chunked swizzle over 4096 blocks: l = gt + 4*(nt + 128*b)
  // XCD = l/512 = b; 4 gt-blocks of a (b,nt) tile are consecutive on one XCD.
  const int bid = blockIdx.x;                  // 0..4095
  const int l   = (bid & 7) * 512 + (bid >> 3);
  const int gt  = l & 3;                       // 128-row group of W/out
  const int nt  = (l >> 2) & 127;
  const int b   = l >> 9;
  const int g0  = gt * 128;                    // block rows: g0 .. g0+127

  // fragment base pointers (shorts); per-tile stride = 4096 shorts
  const short* xtile = xp + ((size_t)(b * 128 + nt) * 16) * 4096
                          + (size_t)(klane * 128 + li) * 8;
  // wave rows: row0 = g0 + w*32 ; rows row0 + fm*16 + li, all in W group gt
  const int row0 = g0 + w * 32;
  const short* wtile = wp + ((size_t)gt * 16) * 4096
                          + (size_t)(klane * 128 + (row0 & 127) + li) * 8;

  f32x4 acc[2][8] = {};   // [fm][fn]; fn == k plane

#pragma unroll 4
  for (int kt = 0; kt < 16; ++kt) {
    const short* xt = xtile + (size_t)kt * 4096;
    const short* wt = wtile + (size_t)kt * 4096;
    bf16x8 afr[2], bfr[8];
#pragma unroll
    for (int fm = 0; fm < 2; ++fm)
      afr[fm] = *(const bf16x8*)(wt + fm * (16 * 8));   // +16 chunks
#pragma unroll
    for (int fn = 0; fn < 8; ++fn)
      bfr[fn] = *(const bf16x8*)(xt + fn * (16 * 8));   // +16 chunks
#pragma unroll
    for (int fm = 0; fm < 2; ++fm)
#pragma unroll
      for (int fn = 0; fn < 8; ++fn)
        acc[fm][fn] = __builtin_amdgcn_mfma_f32_16x16x32_bf16(
            afr[fm], bfr[fn], acc[fm][fn], 0, 0, 0);
  }

  // ---- epilogue: kf (fp32 x, Killing Gram) + branch + store, coalesced ----
  // D frag: col = li (nn), row-in-16 = klane*4 + r
  const int n0 = nt * 16;
#pragma unroll
  for (int fm = 0; fm < 2; ++fm) {
#pragma unroll
    for (int r = 0; r < 4; ++r) {
      const int g = g0 + w * 32 + fm * 16 + klane * 4 + r;
      const size_t base = ((size_t)(b * 512 + g)) * 16384 + n0 + li;
      float xk[8];
#pragma unroll
      for (int k = 0; k < 8; ++k) xk[k] = x[base + (size_t)k * 2048];
      // c_l = (G x)_l ; G: 12@(0,0),(4,4); -6@(0,4); 6@{1,3},{2,6},{5,7}
      const float c0 = 12.f * xk[0] - 6.f * xk[4];
      const float c4 = 12.f * xk[4] - 6.f * xk[0];
      const float c1 = 6.f * xk[3];
      const float c2 = 6.f * xk[6];
      const float c3 = 6.f * xk[1];
      const float c5 = 6.f * xk[7];
      const float c6 = 6.f * xk[2];
      const float c7 = 6.f * xk[5];
      const float kf = c0 * acc[fm][0][r] + c1 * acc[fm][1][r]
                     + c2 * acc[fm][2][r] + c3 * acc[fm][3][r]
                     + c4 * acc[fm][4][r] + c5 * acc[fm][5][r]
                     + c6 * acc[fm][6][r] + c7 * acc[fm][7][r];
#pragma unroll
      for (int k = 0; k < 8; ++k) {
        const float o = (kf <= 0.f) ? xk[k] : fmaf(kf, acc[fm][k][r], xk[k]);
        out[base + (size_t)k * 2048] = o;
      }
    }
  }
}

// ---------------- fallback: proven R2 kernel (ws too small) ----------------
__global__ __launch_bounds__(512, 4) void lnkill_fused(
    const float* __restrict__ x, const float* __restrict__ W,
    float* __restrict__ out) {
  __shared__ __align__(16) short ldsA[2][4096];
  __shared__ __align__(16) short ldsB[2][4096];

  const int tid  = threadIdx.x;
  const int lane = tid & 63;
  const int w    = tid >> 6;

  const int bid = blockIdx.x;
  const int l   = (bid & 7) * 512 + (bid >> 3);
  const int gt  = l & 3;
  const int nt  = (l >> 2) & 127;
  const int b   = l >> 9;
  const int g0  = gt * 128;
  const int n0  = nt * 16;

  const int cm = tid & 127;
  const int fg = tid >> 7;
  const float* xs   = x + (((size_t)(b * 512 + fg * 8)) * 8 + (cm >> 4)) * 2048
                        + n0 + (cm & 15);
  const float* Wrow = W + (size_t)(g0 + cm) * 512 + fg * 8;

  f32x4 acc[8] = {};

  {
    float xv[8];
#pragma unroll
    for (int j = 0; j < 8; ++j) xv[j] = xs[(size_t)j * 16384];
    float4 wv[2];
    const float4* wpp = (const float4*)Wrow;
    wv[0] = wpp[0]; wv[1] = wpp[1];
    const float* wf = (const float*)wv;
    bf16x8 vb, va;
#pragma unroll
    for (int j = 0; j < 8; ++j) {
      vb[j] = (short)f2bf(xv[j]);
      va[j] = (short)f2bf(wf[j]);
    }
    *(bf16x8*)&ldsB[0][(fg * 128 + cm) * 8] = vb;
    *(bf16x8*)&ldsA[0][(fg * 128 + cm) * 8] = va;
  }
  __syncthreads();

  const int klane = lane >> 4;
  const int li    = lane & 15;

  for (int kt = 0; kt < 16; ++kt) {
    const int cur = kt & 1;
    float xv[8];
    float4 wv[2];
    if (kt < 15) {
      const float* xpn = xs + (size_t)(kt + 1) * 32 * 16384;
#pragma unroll
      for (int j = 0; j < 8; ++j) xv[j] = xpn[(size_t)j * 16384];
      const float4* wpp = (const float4*)(Wrow + (kt + 1) * 32);
      wv[0] = wpp[0]; wv[1] = wpp[1];
    }
    {
      const short* Ac = ldsA[cur];
      const short* Bc = ldsB[cur];
      bf16x8 afr = *(const bf16x8*)&Ac[(klane * 128 + w * 16 + li) * 8];
#pragma unroll
      for (int fn = 0; fn < 8; ++fn) {
        bf16x8 bfr = *(const bf16x8*)&Bc[(klane * 128 + fn * 16 + li) * 8];
        acc[fn] = __builtin_amdgcn_mfma_f32_16x16x32_bf16(afr, bfr, acc[fn], 0, 0, 0);
      }
    }
    if (kt < 15) {
      const int nxt = cur ^ 1;
      const float* wf = (const float*)wv;
      bf16x8 vb, va;
#pragma unroll
      for (int j = 0; j < 8; ++j) {
        vb[j] = (short)f2bf(xv[j]);
        va[j] = (short)f2bf(wf[j]);
      }
      __syncthreads();
      *(bf16x8*)&ldsB[nxt][(fg * 128 + cm) * 8] = vb;
      *(bf16x8*)&ldsA[nxt][(fg * 128 + cm) * 8] = va;
      __syncthreads();
    }
  }

#pragma unroll
  for (int r = 0; r < 4; ++r) {
    const int g = g0 + w * 16 + klane * 4 + r;
    const size_t base = ((size_t)(b * 512 + g)) * 16384 + n0 + li;
    float xk[8];
#pragma unroll
    for (int k = 0; k < 8; ++k) xk[k] = x[base + (size_t)k * 2048];
    const float c0 = 12.f * xk[0] - 6.f * xk[4];
    const float c4 = 12.f * xk[4] - 6.f * xk[0];
    const float c1 = 6.f * xk[3];
    const float c2 = 6.f * xk[6];
    const float c3 = 6.f * xk[1];
    const float c5 = 6.f * xk[7];
    const float c6 = 6.f * xk[2];
    const float c7 = 6.f * xk[5];
    const float kf = c0 * acc[0][r] + c1 * acc[1][r]
                   + c2 * acc[2][r] + c3 * acc[3][r]
                   + c4 * acc[4][r] + c5 * acc[5][r]
                   + c6 * acc[6][r] + c7 * acc[7][r];
#pragma unroll
    for (int k = 0; k < 8; ++k) {
      const float o = (kf <= 0.f) ? xk[k] : fmaf(kf, acc[k][r], xk[k]);
      out[base + (size_t)k * 2048] = o;
    }
  }
}

extern "C" void kernel_launch(void* const* d_in, const int* in_sizes, int n_in,
                              void* d_out, int out_size, void* d_ws, size_t ws_size,
                              hipStream_t stream) {
  const float* x = (const float*)d_in[0];
  const float* W = (const float*)d_in[1];
  float* out = (float*)d_out;

  const size_t need = (size_t)512 * 1024 + (size_t)8388608 * 16;  // 0.5MB + 128MiB
  if (ws_size >= need) {
    short* wp = (short*)d_ws;                       // 512 KB
    short* xp = (short*)d_ws + 262144;              // after 512 KB
    prepack_w<<<dim3(128),   dim3(256), 0, stream>>>(W, wp);
    prepack_x<<<dim3(32768), dim3(256), 0, stream>>>(x, xp);
    // 4096 blocks: 4 gt x 128 nt x 8 b ; 256 thr (4 waves x 32 g-rows)
    lnkill_gemm_nolds<<<dim3(4096), dim3(256), 0, stream>>>(xp, wp, x, out);
  } else {
    lnkill_fused<<<dim3(4096), dim3(512), 0, stream>>>(x, W, out);
  }
}

// Round 9
// 251.485 us; speedup vs baseline: 1.3732x; 1.3732x over previous
//
#include <hip/hip_runtime.h>

// LNKillingRelu: out = where(kf<=0, x, x + kf*d)
//   d[b,g,k,n]  = sum_f W[g,f] x[b,f,k,n]          (bf16 MFMA GEMM, K=512)
//   kf[b,g,n]   = sum_{k,l} x[b,g,k,n] G[k,l] d[b,g,l,n]   (fp32, G = sl3 Killing)
// x: [8,512,8,2048] f32, W: [512,512] f32, out same shape as x.
//
// R9: FULL-G block. Block = ALL 512 g-rows x 16 n for one (b,nt):
//  - x slice staged+cvt'd ONCE (R2-R8 staged it 4x; the 84us x-prepack is gone)
//  - per-iter work 4x bigger (32 MFMA/wave) -> the invariant ~2k-cycle
//    latency+sync envelope per iteration amortizes 4x better
//  - W pre-packed bf16 (512KB, ~2us prepass), staged via global_load_lds into
//    a TRIPLE-buffered 32KB A-tile (depth-2 prefetch, counted vmcnt, raw
//    barriers, no vmcnt drain -- R6-proven scheme; 3 bufs because A(kt+2) is
//    in flight while A(kt+1) pending and A(kt) being read)
//  - x tile (8KB bf16) double-buffered via R2 register path (8 f-strided
//    loads + cvt), 1x total; 2 raw barriers/iter (write/read race)
//  - epilogue in-register Killing form, fp32 x re-read (L2-hot), coalesced.

typedef short bf16x8 __attribute__((ext_vector_type(8)));
typedef float f32x4 __attribute__((ext_vector_type(4)));

__device__ __forceinline__ unsigned short f2bf(float f) {
  unsigned int u = __float_as_uint(f);
  u += 0x7fffu + ((u >> 16) & 1u);   // round-to-nearest-even
  return (unsigned short)(u >> 16);
}

__device__ __forceinline__ void gload16(const void* g, void* l) {
  typedef const __attribute__((address_space(1))) unsigned int* gp_t;
  typedef __attribute__((address_space(3))) unsigned int* lp_t;
  __builtin_amdgcn_global_load_lds((gp_t)g, (lp_t)l, 16, 0, 0);
}

// ---------------- prepass: pack W -> bf16 tiles (512 KB) ----------------
// chunk cid = (kt*4+kg)*512 + row ; elems j=0..7 -> f = kt*32 + kg*8 + j
__global__ __launch_bounds__(256) void prepack_w(const float* __restrict__ W,
                                                 short* __restrict__ wp) {
  const int cid = blockIdx.x * 256 + threadIdx.x;    // 32768 chunks
  const int row  = cid & 511;
  const int kgkt = cid >> 9;
  const int kg = kgkt & 3;
  const int kt = kgkt >> 2;
  const float* src = W + (size_t)row * 512 + kt * 32 + kg * 8;
  bf16x8 v;
#pragma unroll
  for (int j = 0; j < 8; ++j) v[j] = (short)f2bf(src[j]);
  *(bf16x8*)&wp[(size_t)cid * 8] = v;
}

// ---------------- main fused GEMM + Killing epilogue (full g) ----------------
__global__ __launch_bounds__(512, 2) void lnkill_fullg(
    const float* __restrict__ x, const short* __restrict__ wp,
    float* __restrict__ out) {
  __shared__ __align__(16) short ldsA[3][16384];  // W tile: [kg(4)][row(512)][8]
  __shared__ __align__(16) short ldsB[2][4096];   // x tile: [kg(4)][c(128)][8]

  const int tid   = threadIdx.x;
  const int lane  = tid & 63;
  const int w     = tid >> 6;      // wave 0..7; wave owns rows w*64..w*64+63
  const int klane = lane >> 4;     // kg 0..3
  const int li    = lane & 15;

  const int bid = blockIdx.x;      // 0..1023 ; no swizzle needed (no x sharing)
  const int nt  = bid & 127;
  const int b   = bid >> 7;
  const int n0  = nt * 16;

  // x staging map (R2): cm = c-col, fg = f-subgroup
  const int cm = tid & 127;
  const int fg = tid >> 7;         // 0..3
  const float* xs = x + (((size_t)(b * 512 + fg * 8)) * 8 + (cm >> 4)) * 2048
                      + n0 + (cm & 15);

  f32x4 acc[4][8] = {};            // [fm][fn]; fn == k plane
  float rB[2][8];                  // x prefetch regsets; B(t) lives in rB[t&1]

  // ---- prologue ----
  // A(0), A(1) via global_load_lds (4 chunks/thread each)
#pragma unroll
  for (int s = 0; s < 4; ++s) {
    const int c = tid + s * 512;
    gload16(wp + (size_t)c * 8, &ldsA[0][c * 8]);
  }
  // B(0): load + cvt + write directly
  {
    float b0[8];
#pragma unroll
    for (int j = 0; j < 8; ++j) b0[j] = xs[(size_t)j * 16384];
    bf16x8 v;
#pragma unroll
    for (int j = 0; j < 8; ++j) v[j] = (short)f2bf(b0[j]);
    *(bf16x8*)&ldsB[0][(fg * 128 + cm) * 8] = v;
  }
#pragma unroll
  for (int s = 0; s < 4; ++s) {
    const int c = tid + s * 512;
    gload16(wp + (size_t)(2048 + c) * 8, &ldsA[1][c * 8]);
  }
  // B(1) -> rB[1]
#pragma unroll
  for (int j = 0; j < 8; ++j) rB[1][j] = xs[(size_t)(32 + j) * 16384];

#pragma unroll
  for (int kt = 0; kt < 16; ++kt) {
    // 1) stage B(kt+1): cvt regs (loaded a full iter ago) -> ldsB[(kt+1)&1]
    if (kt < 15) {
      bf16x8 v;
#pragma unroll
      for (int j = 0; j < 8; ++j) v[j] = (short)f2bf(rB[(kt + 1) & 1][j]);
      *(bf16x8*)&ldsB[(kt + 1) & 1][(fg * 128 + cm) * 8] = v;
    }
    // 2) issue A(kt+2) -> ldsA[(kt+2)%3] ; 3) issue B(kt+2) -> rB[kt&1]
    if (kt < 14) {
#pragma unroll
      for (int s = 0; s < 4; ++s) {
        const int c = tid + s * 512;
        gload16(wp + (size_t)((kt + 2) * 2048 + c) * 8,
                &ldsA[(kt + 2) % 3][c * 8]);
      }
#pragma unroll
      for (int j = 0; j < 8; ++j)
        rB[kt & 1][j] = xs[(size_t)((kt + 2) * 32 + j) * 16384];
    }
    // 4) sync: wait A(kt) landed (16 newer VMEM ops stay in flight), LDS vis
    if (kt < 14) {
      asm volatile("s_waitcnt vmcnt(16) lgkmcnt(0)" ::: "memory");
    } else if (kt == 14) {
      asm volatile("s_waitcnt vmcnt(4) lgkmcnt(0)" ::: "memory");
    } else {
      asm volatile("s_waitcnt vmcnt(0) lgkmcnt(0)" ::: "memory");
    }
    __builtin_amdgcn_s_barrier();
    __builtin_amdgcn_sched_barrier(0);

    // 5) compute tile kt: 12 ds_read_b128 + 32 MFMA
    {
      const short* Ac = ldsA[kt % 3];
      const short* Bc = ldsB[kt & 1];
      bf16x8 afr[4], bfr[8];
#pragma unroll
      for (int fm = 0; fm < 4; ++fm)
        afr[fm] = *(const bf16x8*)&Ac[(klane * 512 + w * 64 + fm * 16 + li) * 8];
#pragma unroll
      for (int fn = 0; fn < 8; ++fn)
        bfr[fn] = *(const bf16x8*)&Bc[(klane * 128 + fn * 16 + li) * 8];
#pragma unroll
      for (int fm = 0; fm < 4; ++fm)
#pragma unroll
        for (int fn = 0; fn < 8; ++fn)
          acc[fm][fn] = __builtin_amdgcn_mfma_f32_16x16x32_bf16(
              afr[fm], bfr[fn], acc[fm][fn], 0, 0, 0);
    }
    // 6) bare barrier: all reads of this round done before next stage writes
    if (kt < 15) __builtin_amdgcn_s_barrier();
  }

  // ---- epilogue: kf (fp32 x, Killing Gram) + branch + store, coalesced ----
  // D frag: col = li (nn), row-in-16 = klane*4 + r
#pragma unroll
  for (int fm = 0; fm < 4; ++fm) {
#pragma unroll
    for (int r = 0; r < 4; ++r) {
      const int g = w * 64 + fm * 16 + klane * 4 + r;
      const size_t base = ((size_t)(b * 512 + g)) * 16384 + n0 + li;
      float xk[8];
#pragma unroll
      for (int k = 0; k < 8; ++k) xk[k] = x[base + (size_t)k * 2048];
      // c_l = (G x)_l ; G: 12@(0,0),(4,4); -6@(0,4); 6@{1,3},{2,6},{5,7}
      const float c0 = 12.f * xk[0] - 6.f * xk[4];
      const float c4 = 12.f * xk[4] - 6.f * xk[0];
      const float c1 = 6.f * xk[3];
      const float c2 = 6.f * xk[6];
      const float c3 = 6.f * xk[1];
      const float c5 = 6.f * xk[7];
      const float c6 = 6.f * xk[2];
      const float c7 = 6.f * xk[5];
      const float kf = c0 * acc[fm][0][r] + c1 * acc[fm][1][r]
                     + c2 * acc[fm][2][r] + c3 * acc[fm][3][r]
                     + c4 * acc[fm][4][r] + c5 * acc[fm][5][r]
                     + c6 * acc[fm][6][r] + c7 * acc[fm][7][r];
#pragma unroll
      for (int k = 0; k < 8; ++k) {
        const float o = (kf <= 0.f) ? xk[k] : fmaf(kf, acc[fm][k][r], xk[k]);
        out[base + (size_t)k * 2048] = o;
      }
    }
  }
}

// ---------------- fallback: proven R2 kernel (ws too small) ----------------
__global__ __launch_bounds__(512, 4) void lnkill_fused(
    const float* __restrict__ x, const float* __restrict__ W,
    float* __restrict__ out) {
  __shared__ __align__(16) short ldsA[2][4096];
  __shared__ __align__(16) short ldsB[2][4096];

  const int tid  = threadIdx.x;
  const int lane = tid & 63;
  const int w    = tid >> 6;

  const int bid = blockIdx.x;
  const int l   = (bid & 7) * 512 + (bid >> 3);
  const int gt  = l & 3;
  const int nt  = (l >> 2) & 127;
  const int b   = l >> 9;
  const int g0  = gt * 128;
  const int n0  = nt * 16;

  const int cm = tid & 127;
  const int fg = tid >> 7;
  const float* xs   = x + (((size_t)(b * 512 + fg * 8)) * 8 + (cm >> 4)) * 2048
                        + n0 + (cm & 15);
  const float* Wrow = W + (size_t)(g0 + cm) * 512 + fg * 8;

  f32x4 acc[8] = {};

  {
    float xv[8];
#pragma unroll
    for (int j = 0; j < 8; ++j) xv[j] = xs[(size_t)j * 16384];
    float4 wv[2];
    const float4* wpp = (const float4*)Wrow;
    wv[0] = wpp[0]; wv[1] = wpp[1];
    const float* wf = (const float*)wv;
    bf16x8 vb, va;
#pragma unroll
    for (int j = 0; j < 8; ++j) {
      vb[j] = (short)f2bf(xv[j]);
      va[j] = (short)f2bf(wf[j]);
    }
    *(bf16x8*)&ldsB[0][(fg * 128 + cm) * 8] = vb;
    *(bf16x8*)&ldsA[0][(fg * 128 + cm) * 8] = va;
  }
  __syncthreads();

  const int klane = lane >> 4;
  const int li    = lane & 15;

  for (int kt = 0; kt < 16; ++kt) {
    const int cur = kt & 1;
    float xv[8];
    float4 wv[2];
    if (kt < 15) {
      const float* xpn = xs + (size_t)(kt + 1) * 32 * 16384;
#pragma unroll
      for (int j = 0; j < 8; ++j) xv[j] = xpn[(size_t)j * 16384];
      const float4* wpp = (const float4*)(Wrow + (kt + 1) * 32);
      wv[0] = wpp[0]; wv[1] = wpp[1];
    }
    {
      const short* Ac = ldsA[cur];
      const short* Bc = ldsB[cur];
      bf16x8 afr = *(const bf16x8*)&Ac[(klane * 128 + w * 16 + li) * 8];
#pragma unroll
      for (int fn = 0; fn < 8; ++fn) {
        bf16x8 bfr = *(const bf16x8*)&Bc[(klane * 128 + fn * 16 + li) * 8];
        acc[fn] = __builtin_amdgcn_mfma_f32_16x16x32_bf16(afr, bfr, acc[fn], 0, 0, 0);
      }
    }
    if (kt < 15) {
      const int nxt = cur ^ 1;
      const float* wf = (const float*)wv;
      bf16x8 vb, va;
#pragma unroll
      for (int j = 0; j < 8; ++j) {
        vb[j] = (short)f2bf(xv[j]);
        va[j] = (short)f2bf(wf[j]);
      }
      __syncthreads();
      *(bf16x8*)&ldsB[nxt][(fg * 128 + cm) * 8] = vb;
      *(bf16x8*)&ldsA[nxt][(fg * 128 + cm) * 8] = va;
      __syncthreads();
    }
  }

#pragma unroll
  for (int r = 0; r < 4; ++r) {
    const int g = g0 + w * 16 + klane * 4 + r;
    const size_t base = ((size_t)(b * 512 + g)) * 16384 + n0 + li;
    float xk[8];
#pragma unroll
    for (int k = 0; k < 8; ++k) xk[k] = x[base + (size_t)k * 2048];
    const float c0 = 12.f * xk[0] - 6.f * xk[4];
    const float c4 = 12.f * xk[4] - 6.f * xk[0];
    const float c1 = 6.f * xk[3];
    const float c2 = 6.f * xk[6];
    const float c3 = 6.f * xk[1];
    const float c5 = 6.f * xk[7];
    const float c6 = 6.f * xk[2];
    const float c7 = 6.f * xk[5];
    const float kf = c0 * acc[0][r] + c1 * acc[1][r]
                   + c2 * acc[2][r] + c3 * acc[3][r]
                   + c4 * acc[4][r] + c5 * acc[5][r]
                   + c6 * acc[6][r] + c7 * acc[7][r];
#pragma unroll
    for (int k = 0; k < 8; ++k) {
      const float o = (kf <= 0.f) ? xk[k] : fmaf(kf, acc[k][r], xk[k]);
      out[base + (size_t)k * 2048] = o;
    }
  }
}

extern "C" void kernel_launch(void* const* d_in, const int* in_sizes, int n_in,
                              void* d_out, int out_size, void* d_ws, size_t ws_size,
                              hipStream_t stream) {
  const float* x = (const float*)d_in[0];
  const float* W = (const float*)d_in[1];
  float* out = (float*)d_out;

  if (ws_size >= (size_t)524288) {
    short* wp = (short*)d_ws;                       // 512 KB packed W
    prepack_w<<<dim3(128), dim3(256), 0, stream>>>(W, wp);
    // 1024 blocks: 128 nt x 8 b ; 512 thr (8 waves x 64 g-rows, full 512 g)
    lnkill_fullg<<<dim3(1024), dim3(512), 0, stream>>>(x, wp, out);
  } else {
    lnkill_fused<<<dim3(4096), dim3(512), 0, stream>>>(x, W, out);
  }
}